// Round 4
// baseline (5280.435 us; speedup 1.0000x reference)
//
#include <hip/hip_runtime.h>
#include <cmath>

namespace {
constexpr int B_ = 16, T_ = 512, P_ = 256, E_ = 128, NB_ = 4, K_ = 4;

__device__ __forceinline__ float rcpf(float x) { return __builtin_amdgcn_rcpf(x); }
__device__ __forceinline__ float fast_tanh(float x) {
    float a = fabsf(x);
    float t = __expf(-2.0f * a);
    float r = 1.0f - 2.0f * t * rcpf(1.0f + t);
    return copysignf(r, x);
}
// barrier ordering LDS only (no vmcnt drain)
__device__ __forceinline__ void bar_lds() {
    asm volatile("s_waitcnt lgkmcnt(0)\n\ts_barrier" ::: "memory");
}
__device__ __forceinline__ float bcast(float v, int l) {
    return __int_as_float(__builtin_amdgcn_readlane(__float_as_int(v), l));
}
}

// 1 block / batch. ring (128 KiB) in LDS. wave owns e in [wave*32,wave*32+32);
// lanes l, l+32 duplicate e (khalf splits gather offsets 0-4/5-8 and scatter
// row parity). Matvec: s broadcast via v_readlane (SGPR operand, VALU pipe).
// Scatter: khalf owns rows == khalf (mod 2) for every bot -> sole owner per
// (row,e) -> deterministic; single ds_add_f32 per location.
__global__ __launch_bounds__(256, 1)
void swarm_ring_kernel(const float* __restrict__ x,            // (B,T,8)
                       const float* __restrict__ W_in,         // (8,E)
                       const float* __restrict__ b_in,         // (E)
                       const float* __restrict__ W_out,        // (E,8)
                       const float* __restrict__ b_out,        // (8)
                       const float* __restrict__ W_p,          // (E,E)
                       const float* __restrict__ b_p,          // (E)
                       const float* __restrict__ ptr_dest,     // (NB,P)
                       const float* __restrict__ jump_W,       // (NB,E)
                       const float* __restrict__ jump_b,       // (NB)
                       const float* __restrict__ ctx_strength, // (NB)
                       const float* __restrict__ phase_bias,   // (NB,E)
                       const float* __restrict__ pointer_init, // (NB,B)
                       float* __restrict__ out)                // (B,T,8)
{
    __shared__ alignas(16) float ring[P_ * E_];   // 128 KiB
    __shared__ alignas(16) float s_buf[2 * E_];
    __shared__ alignas(16) float red[16];         // jump dots
    __shared__ alignas(16) float redo[32];        // out dots

    const int tid   = threadIdx.x;
    const int b     = blockIdx.x;
    const int wave  = tid >> 6;
    const int lane  = tid & 63;
    const int khalf = lane >> 5;
    const int e     = (wave << 5) | (lane & 31);

    for (int k4 = tid; k4 < P_ * E_ / 4; k4 += 256)
        ((float4*)ring)[k4] = make_float4(0.f, 0.f, 0.f, 0.f);

    float wp[128];                                 // full column W_p[:,e]
    #pragma unroll
    for (int k = 0; k < 128; ++k) wp[k] = W_p[k * E_ + e];

    const float bin_r = b_in[e];
    const float bp_r  = b_p[e];
    float win_r[8];
    #pragma unroll
    for (int k = 0; k < 8; ++k) win_r[k] = W_in[k * E_ + e];
    float wsel[4];                                 // W_out[e][khalf*4+u]
    #pragma unroll
    for (int u = 0; u < 4; ++u) wsel[u] = W_out[e * 8 + khalf * 4 + u];

    float pb_r[NB_], jw_r[NB_], sigc[NB_], jb_r[NB_], hid[NB_], ptrv[NB_];
    #pragma unroll
    for (int i = 0; i < NB_; ++i) {
        pb_r[i] = 0.1f * phase_bias[i * E_ + e];
        jw_r[i] = jump_W[i * E_ + e];
        sigc[i] = 1.0f / (1.0f + __expf(-ctx_strength[i]));
        jb_r[i] = jump_b[i];
        hid[i]  = 0.0f;
        ptrv[i] = pointer_init[i * B_ + b];
    }
    const float bout_r = (tid < 8) ? b_out[tid] : 0.0f;

    const float* xb = x + (size_t)b * T_ * 8;
    float xt[8];
    {
        float4 a0 = ((const float4*)xb)[0], a1 = ((const float4*)xb)[1];
        xt[0]=a0.x; xt[1]=a0.y; xt[2]=a0.z; xt[3]=a0.w;
        xt[4]=a1.x; xt[5]=a1.y; xt[6]=a1.z; xt[7]=a1.w;
    }

    const float Cw1 = 0.8824969f, Cw2 = 0.60653066f, Cw3 = 0.32465247f, Cw4 = 0.13533528f;
    const float Dw1 = 0.7788008f, Dw2 = 0.36787944f, Dw3 = 0.105399225f, Dw4 = 0.018315639f;

    bar_lds();

    for (int t = 0; t < T_; ++t) {
        // ---- geometry, softmax weights, jump-target prefetch
        int   baseA[NB_];
        float fA[NB_], psinv[NB_], jt[NB_], wgt[NB_][9];
        #pragma unroll
        for (int i = 0; i < NB_; ++i) {
            const float p = ptrv[i];
            const int base = (int)p;
            baseA[i] = base;
            jt[i] = ptr_dest[i * P_ + base];
            const float f = p - (float)base;
            fA[i] = f;
            const float r  = __expf(0.25f * f);
            const float r2 = r * r, r3 = r2 * r, r4 = r2 * r2;
            const float ri = rcpf(r), ri2 = ri * ri, ri3 = ri2 * ri, ri4 = ri2 * ri2;
            float p0 = Cw4*ri4, p1 = Cw3*ri3, p2 = Cw2*ri2, p3 = Cw1*ri, p4 = 1.0f,
                  p5 = Cw1*r,  p6 = Cw2*r2,  p7 = Cw3*r3,  p8 = Cw4*r4;
            const float sum = ((p0+p1)+(p2+p3)) + ((p4+p5)+(p6+p7)) + p8;
            const float inv = rcpf(sum);
            psinv[i] = inv;
            wgt[i][0]=p0*inv; wgt[i][1]=p1*inv; wgt[i][2]=p2*inv; wgt[i][3]=p3*inv;
            wgt[i][4]=p4*inv; wgt[i][5]=p5*inv; wgt[i][6]=p6*inv; wgt[i][7]=p7*inv;
            wgt[i][8]=p8*inv;
        }

        // ---- gathers (khalf-split offsets; weight picked via cndmask, no
        //      runtime indexing of wgt) + ctx partials, combined via xor32
        float ctxp[NB_];
        #pragma unroll
        for (int i = 0; i < NB_; ++i) {
            float c = 0.f;
            #pragma unroll
            for (int u = 0; u < 5; ++u) {
                const float wlo = wgt[i][u];
                const float whi = (u == 0) ? 0.f : wgt[i][u + 4];
                const float wv  = khalf ? whi : wlo;
                const int row = (baseA[i] + u + (khalf << 2) - K_) & (P_ - 1);
                c = fmaf(wv, ring[row * E_ + e], c);
            }
            c += __shfl_xor(c, 32);
            ctxp[i] = c;
        }

        // ---- cross-bot correction coefficients (pointers only)
        float coefm[NB_][NB_];
        #pragma unroll
        for (int j = 1; j < NB_; ++j) {
            #pragma unroll
            for (int i = 0; i < j; ++i) {
                const int dd = ((baseA[j] - baseA[i] + 128) & 255) - 128;
                float c = 0.f;
                if (dd >= -8 && dd <= 8) {
                    const float A = (float)dd - fA[i];
                    const float s  = __expf(-0.25f * (A - fA[j]));
                    const float G  = __expf(0.125f * (fA[i] * fA[i] - A * A));
                    const float s2p = s * s, s3p = s2p * s, s4p = s2p * s2p;
                    const float si = rcpf(s), si2 = si * si, si3 = si2 * si, si4 = si2 * si2;
                    float acc = 0.f;
                    acc += (dd >= 0)              ? Dw4 * si4 : 0.f;
                    acc += (dd >= -1 && dd <= 7)  ? Dw3 * si3 : 0.f;
                    acc += (dd >= -2 && dd <= 6)  ? Dw2 * si2 : 0.f;
                    acc += (dd >= -3 && dd <= 5)  ? Dw1 * si  : 0.f;
                    acc += (dd >= -4 && dd <= 4)  ? 1.0f      : 0.f;
                    acc += (dd >= -5 && dd <= 3)  ? Dw1 * s   : 0.f;
                    acc += (dd >= -6 && dd <= 2)  ? Dw2 * s2p : 0.f;
                    acc += (dd >= -7 && dd <= 1)  ? Dw3 * s3p : 0.f;
                    acc += (dd <= 0)              ? Dw4 * s4p : 0.f;
                    c = psinv[i] * psinv[j] * G * acc;
                }
                coefm[j][i] = c;
            }
        }

        float inp = bin_r;
        #pragma unroll
        for (int k = 0; k < 8; ++k) inp = fmaf(xt[k], win_r[k], inp);

        float xtn[8];
        if (t + 1 < T_) {
            float4 a0 = ((const float4*)(xb + (t + 1) * 8))[0];
            float4 a1 = ((const float4*)(xb + (t + 1) * 8))[1];
            xtn[0]=a0.x; xtn[1]=a0.y; xtn[2]=a0.z; xtn[3]=a0.w;
            xtn[4]=a1.x; xtn[5]=a1.y; xtn[6]=a1.z; xtn[7]=a1.w;
        } else {
            #pragma unroll
            for (int k = 0; k < 8; ++k) xtn[k] = 0.f;
        }

        // ---- serial bot chain
        float sv[NB_];
        #pragma unroll
        for (int j = 0; j < NB_; ++j) {
            float ctx = ctxp[j];
            #pragma unroll
            for (int i = 0; i < j; ++i) ctx = fmaf(coefm[j][i], sv[i], ctx);
            const float s1 = fast_tanh(fmaf(sigc[j], ctx, inp + pb_r[j] + hid[j]));
            if (lane < 32) s_buf[(j & 1) * E_ + e] = s1;
            bar_lds();                                    // s broadcast ready

            const float2 sl = ((const float2*)(s_buf + (j & 1) * E_))[lane];
            float a0 = 0.f, a1 = 0.f;
            #pragma unroll
            for (int q = 0; q < 64; ++q) {                // SGPR broadcast matvec
                const float sa = bcast(sl.x, q);          // s[2q]
                const float sb = bcast(sl.y, q);          // s[2q+1]
                a0 = fmaf(sa, wp[2 * q], a0);
                a1 = fmaf(sb, wp[2 * q + 1], a1);
            }
            const float s2 = fast_tanh(a0 + a1 + bp_r);
            sv[j] = s2; hid[j] = s2;

            // parity-owned scatter: khalf owns rows == khalf (mod 2);
            // o0 = (base ^ khalf) & 1 selects this half's offset parity.
            const int o0 = (baseA[j] ^ khalf) & 1;
            #pragma unroll
            for (int u = 0; u < 4; ++u) {
                const float wa = wgt[j][2 * u];           // o0 == 0 case
                const float wb = wgt[j][2 * u + 1];       // o0 == 1 case
                const float wv = o0 ? wb : wa;
                const int row = (baseA[j] + 2 * u + o0 - K_) & (P_ - 1);
                atomicAdd(&ring[row * E_ + e], wv * s2);
            }
            if (o0 == 0) {
                const int row = (baseA[j] + 8 - K_) & (P_ - 1);
                atomicAdd(&ring[row * E_ + e], wgt[j][8] * s2);
            }
            // no barrier: next bot uses step-start gathers + coef corrections
        }

        // ---- jump dots (khalf0: bots 0,1; khalf1: bots 2,3)
        {
            float va = khalf ? sv[2] * jw_r[2] : sv[0] * jw_r[0];
            float vb = khalf ? sv[3] * jw_r[3] : sv[1] * jw_r[1];
            #pragma unroll
            for (int off = 1; off < 32; off <<= 1) {
                va += __shfl_xor(va, off);
                vb += __shfl_xor(vb, off);
            }
            if ((lane & 31) == 0)
                ((float2*)red)[wave * 2 + khalf] = make_float2(va, vb);
        }

        // ---- out dots (khalf0: dims 0-3; khalf1: dims 4-7)
        {
            const float ssum = (sv[0] + sv[1]) + (sv[2] + sv[3]);
            float u0 = ssum * wsel[0], u1 = ssum * wsel[1],
                  u2 = ssum * wsel[2], u3 = ssum * wsel[3];
            #pragma unroll
            for (int off = 1; off < 32; off <<= 1) {
                u0 += __shfl_xor(u0, off); u1 += __shfl_xor(u1, off);
                u2 += __shfl_xor(u2, off); u3 += __shfl_xor(u3, off);
            }
            if ((lane & 31) == 0)
                ((float4*)redo)[wave * 2 + khalf] = make_float4(u0, u1, u2, u3);
        }

        bar_lds();                                        // scatters + red/redo visible

        {
            const float4 r0 = ((const float4*)red)[0];
            const float4 r1 = ((const float4*)red)[1];
            const float4 r2 = ((const float4*)red)[2];
            const float4 r3 = ((const float4*)red)[3];
            const float zz[4] = {
                ((r0.x + r1.x) + (r2.x + r3.x)) + jb_r[0],
                ((r0.y + r1.y) + (r2.y + r3.y)) + jb_r[1],
                ((r0.z + r1.z) + (r2.z + r3.z)) + jb_r[2],
                ((r0.w + r1.w) + (r2.w + r3.w)) + jb_r[3]};
            #pragma unroll
            for (int i = 0; i < NB_; ++i) {
                float np;
                if (zz[i] > 0.0f) np = jt[i];
                else { np = ptrv[i] + 1.0f; if (np >= 256.0f) np -= 256.0f; }
                ptrv[i] = np;
            }
        }
        if (tid < 8) {
            const float ov = 0.25f * ((redo[tid] + redo[8 + tid]) +
                                      (redo[16 + tid] + redo[24 + tid])) + bout_r;
            out[((size_t)b * T_ + t) * 8 + tid] = ov;
        }

        #pragma unroll
        for (int k = 0; k < 8; ++k) xt[k] = xtn[k];
    }
}

extern "C" void kernel_launch(void* const* d_in, const int* in_sizes, int n_in,
                              void* d_out, int out_size, void* d_ws, size_t ws_size,
                              hipStream_t stream) {
    (void)in_sizes; (void)n_in; (void)out_size; (void)d_ws; (void)ws_size;
    swarm_ring_kernel<<<dim3(B_), dim3(256), 0, stream>>>(
        (const float*)d_in[0],  (const float*)d_in[1],  (const float*)d_in[2],
        (const float*)d_in[3],  (const float*)d_in[4],  (const float*)d_in[5],
        (const float*)d_in[6],  (const float*)d_in[7],  (const float*)d_in[8],
        (const float*)d_in[9],  (const float*)d_in[10], (const float*)d_in[11],
        (const float*)d_in[12], (float*)d_out);
}